// Round 4
// baseline (180.454 us; speedup 1.0000x reference)
//
#include <hip/hip_runtime.h>
#include <stdint.h>

#define N_NODES 2048
#define N_BATCH 4
#define ROWS_PER_BLOCK 8
#define THREADS 512   // 8 waves, one row per wave

__device__ __forceinline__ uint32_t bf16rn(float x) {
    uint32_t u = __float_as_uint(x);
    u += 0x7fffu + ((u >> 16) & 1u);
    return u >> 16;
}

// LDS = 32 KB table only -> occupancy capped by waves: 4 blocks/CU, 32 waves/CU.
// (512, 8): 8 waves/SIMD -> VGPR cap 64; explicit load arrays use ~56.
__global__ __launch_bounds__(THREADS, 8) void kuramoto_kernel(
    const float* __restrict__ theta,
    const float* __restrict__ gamma,
    const float* __restrict__ W,
    const float* __restrict__ alpha,
    float* __restrict__ out)
{
    // per j, 4 dwords: dword d = (bf16(cos th_jd)<<16) | bf16(sin th_jd)
    __shared__ uint4 table[N_NODES];

    const int tid  = threadIdx.x;
    const int lane = tid & 63;
    const int wave = tid >> 6;
    const int b    = blockIdx.x >> 8;                       // 256 blocks per batch
    const int i    = ((blockIdx.x & 255) * ROWS_PER_BLOCK) + wave;  // row in batch

    // ---- Phase 1: stage sin/cos(theta[b,:,:]) into LDS, bf16-packed ----
    const float* thb = theta + (size_t)b * (N_NODES * 4);
    #pragma unroll
    for (int g = 0; g < N_NODES / THREADS; ++g) {
        const int j = tid + g * THREADS;
        const float4 u = *(const float4*)(thb + (size_t)j * 4);  // 16B coalesced
        const float th[4] = {u.x, u.y, u.z, u.w};
        uint32_t p[4];
        #pragma unroll
        for (int d = 0; d < 4; ++d) {
            float s, c;
            __sincosf(th[d], &s, &c);
            p[d] = (bf16rn(c) << 16) | bf16rn(s);
        }
        table[j] = make_uint4(p[0], p[1], p[2], p[3]);  // lane stride 16B: conflict-free
    }
    __syncthreads();

    // ---- Phase 2: complex accumulation, software-pipelined ----
    // coupling_d = c_i*im_d - s_i*re_d
    //   im_d = sum_j (A*s_jd - B*c_jd),  re_d = sum_j (A*c_jd + B*s_jd)
    //   A = W*cos(alpha), B = W*sin(alpha)
    const size_t rowbase = ((size_t)b * N_NODES + i) * N_NODES;
    const float* Wr = W + rowbase;
    const float* Ar = alpha + rowbase;

    float re[4] = {0.f, 0.f, 0.f, 0.f};
    float im[4] = {0.f, 0.f, 0.f, 0.f};

    // 4 groups of 8 j-steps (j = g*512 + k*64 + lane). Double-buffered register
    // pipeline: 16 dword loads (4 KB/wave) in flight while computing the
    // previous group — breaks the load->waitcnt->compute convoy (VGPR=24 in
    // the previous build showed the compiler serialized memory).
    float wcur[8], acur[8], wnxt[8], anxt[8];
    #pragma unroll
    for (int k = 0; k < 8; ++k) {
        wcur[k] = Wr[lane + 64 * k];
        acur[k] = Ar[lane + 64 * k];
    }

    #pragma unroll
    for (int g = 0; g < 4; ++g) {
        if (g < 3) {
            const int nb = (g + 1) * 512 + lane;
            #pragma unroll
            for (int k = 0; k < 8; ++k) {
                wnxt[k] = Wr[nb + 64 * k];
                anxt[k] = Ar[nb + 64 * k];
            }
        }
        #pragma unroll
        for (int k = 0; k < 8; ++k) {
            const int j = g * 512 + 64 * k + lane;
            float sa, ca;
            __sincosf(acur[k], &sa, &ca);
            const float A  = wcur[k] * ca;   // W*cos(alpha)
            const float Bq = wcur[k] * sa;   // W*sin(alpha)
            const uint4 t = table[j];        // ds_read_b128, 16B/lane: conflict-free
            const uint32_t tw[4] = {t.x, t.y, t.z, t.w};
            #pragma unroll
            for (int d = 0; d < 4; ++d) {
                const float s = __uint_as_float(tw[d] << 16);
                const float c = __uint_as_float(tw[d] & 0xffff0000u);
                re[d] = fmaf(A,  c, re[d]);
                re[d] = fmaf(Bq, s, re[d]);
                im[d] = fmaf(A,  s, im[d]);
                im[d] = fmaf(-Bq, c, im[d]);
            }
        }
        #pragma unroll
        for (int k = 0; k < 8; ++k) {
            wcur[k] = wnxt[k];
            acur[k] = anxt[k];
        }
    }

    // ---- Reduction: 6-stage butterfly over 64 lanes, 8 accumulators ----
    #pragma unroll
    for (int stage = 1; stage < 64; stage <<= 1) {
        #pragma unroll
        for (int d = 0; d < 4; ++d) {
            re[d] += __shfl_xor(re[d], stage, 64);
            im[d] += __shfl_xor(im[d], stage, 64);
        }
    }

    if (lane == 0) {
        const size_t obase = ((size_t)b * N_NODES + i) * 4;
        const float4 th4 = *(const float4*)(thb + (size_t)i * 4);
        const float4 g4  = *(const float4*)(gamma + obase);
        const float thd[4] = {th4.x, th4.y, th4.z, th4.w};
        const float gd[4]  = {g4.x, g4.y, g4.z, g4.w};
        float t[4];
        float s2 = 0.0f;
        #pragma unroll
        for (int d = 0; d < 4; ++d) {
            float s_i, c_i;
            __sincosf(thd[d], &s_i, &c_i);
            const float coup = (c_i * im[d] - s_i * re[d]) * (1.0f / (float)N_NODES);
            t[d] = gd[d] + coup;   // theta + (gamma-theta) + coupling  (DT=ATTR=1)
            s2 = fmaf(t[d], t[d], s2);
        }
        const float inv = 1.0f / fmaxf(sqrtf(s2), 1e-6f);
        *(float4*)(out + obase) = make_float4(t[0]*inv, t[1]*inv, t[2]*inv, t[3]*inv);
    }
}

extern "C" void kernel_launch(void* const* d_in, const int* in_sizes, int n_in,
                              void* d_out, int out_size, void* d_ws, size_t ws_size,
                              hipStream_t stream) {
    const float* theta = (const float*)d_in[0];
    const float* gamma = (const float*)d_in[1];
    const float* W     = (const float*)d_in[2];
    const float* alpha = (const float*)d_in[3];
    float* out = (float*)d_out;

    const int grid = (N_BATCH * N_NODES) / ROWS_PER_BLOCK;  // 1024 blocks = 4/CU
    hipLaunchKernelGGL(kuramoto_kernel, dim3(grid), dim3(THREADS), 0, stream,
                       theta, gamma, W, alpha, out);
}

// Round 5
// 153.561 us; speedup vs baseline: 1.1751x; 1.1751x over previous
//
#include <hip/hip_runtime.h>
#include <stdint.h>

#define N_NODES 2048
#define N_BATCH 4
#define ROWS_PER_BLOCK 8
#define THREADS 512   // 8 waves, one row per wave

__device__ __forceinline__ uint32_t bf16rn(float x) {
    uint32_t u = __float_as_uint(x);
    u += 0x7fffu + ((u >> 16) & 1u);
    return u >> 16;
}

// LDS = 32 KB table. __launch_bounds__(512, 4): VGPR cap 128 so the depth-8
// register pipeline stays in registers (the (512,8)/64-cap build spilled:
// WRITE_SIZE 96 MB of scratch traffic). 2 blocks/CU = 16 waves/CU; each wave
// keeps 16 dword loads (4 KB) in flight -> ~64 KB/CU, covers ~500cyc latency.
__global__ __launch_bounds__(THREADS, 4) void kuramoto_kernel(
    const float* __restrict__ theta,
    const float* __restrict__ gamma,
    const float* __restrict__ W,
    const float* __restrict__ alpha,
    float* __restrict__ out)
{
    // per j, 4 dwords: dword d = (bf16(cos th_jd)<<16) | bf16(sin th_jd)
    __shared__ uint4 table[N_NODES];

    const int tid  = threadIdx.x;
    const int lane = tid & 63;
    const int wave = tid >> 6;
    const int b    = blockIdx.x >> 8;                       // 256 blocks per batch
    const int i    = ((blockIdx.x & 255) * ROWS_PER_BLOCK) + wave;  // row in batch

    // ---- Phase 1: stage sin/cos(theta[b,:,:]) into LDS, bf16-packed ----
    const float* thb = theta + (size_t)b * (N_NODES * 4);
    #pragma unroll
    for (int g = 0; g < N_NODES / THREADS; ++g) {
        const int j = tid + g * THREADS;
        const float4 u = *(const float4*)(thb + (size_t)j * 4);  // 16B coalesced
        const float th[4] = {u.x, u.y, u.z, u.w};
        uint32_t p[4];
        #pragma unroll
        for (int d = 0; d < 4; ++d) {
            float s, c;
            __sincosf(th[d], &s, &c);
            p[d] = (bf16rn(c) << 16) | bf16rn(s);
        }
        table[j] = make_uint4(p[0], p[1], p[2], p[3]);  // lane stride 16B: conflict-free
    }
    __syncthreads();

    // ---- Phase 2: complex accumulation, software-pipelined ----
    // coupling_d = c_i*im_d - s_i*re_d
    //   im_d = sum_j (A*s_jd - B*c_jd),  re_d = sum_j (A*c_jd + B*s_jd)
    //   A = W*cos(alpha), B = W*sin(alpha)
    const size_t rowbase = ((size_t)b * N_NODES + i) * N_NODES;
    const float* Wr = W + rowbase;
    const float* Ar = alpha + rowbase;

    float re[4] = {0.f, 0.f, 0.f, 0.f};
    float im[4] = {0.f, 0.f, 0.f, 0.f};

    // 4 groups of 8 j-steps (j = g*512 + k*64 + lane), double-buffered in
    // registers: 16 dword loads in flight while computing the previous group.
    float wcur[8], acur[8], wnxt[8], anxt[8];
    #pragma unroll
    for (int k = 0; k < 8; ++k) {
        wcur[k] = Wr[lane + 64 * k];
        acur[k] = Ar[lane + 64 * k];
    }

    #pragma unroll
    for (int g = 0; g < 4; ++g) {
        if (g < 3) {
            const int nb = (g + 1) * 512 + lane;
            #pragma unroll
            for (int k = 0; k < 8; ++k) {
                wnxt[k] = Wr[nb + 64 * k];
                anxt[k] = Ar[nb + 64 * k];
            }
        }
        #pragma unroll
        for (int k = 0; k < 8; ++k) {
            const int j = g * 512 + 64 * k + lane;
            float sa, ca;
            __sincosf(acur[k], &sa, &ca);
            const float A  = wcur[k] * ca;   // W*cos(alpha)
            const float Bq = wcur[k] * sa;   // W*sin(alpha)
            const uint4 t = table[j];        // ds_read_b128, 16B/lane: conflict-free
            const uint32_t tw[4] = {t.x, t.y, t.z, t.w};
            #pragma unroll
            for (int d = 0; d < 4; ++d) {
                const float s = __uint_as_float(tw[d] << 16);
                const float c = __uint_as_float(tw[d] & 0xffff0000u);
                re[d] = fmaf(A,  c, re[d]);
                re[d] = fmaf(Bq, s, re[d]);
                im[d] = fmaf(A,  s, im[d]);
                im[d] = fmaf(-Bq, c, im[d]);
            }
        }
        #pragma unroll
        for (int k = 0; k < 8; ++k) {
            wcur[k] = wnxt[k];
            acur[k] = anxt[k];
        }
    }

    // ---- Reduction: 6-stage butterfly over 64 lanes, 8 accumulators ----
    #pragma unroll
    for (int stage = 1; stage < 64; stage <<= 1) {
        #pragma unroll
        for (int d = 0; d < 4; ++d) {
            re[d] += __shfl_xor(re[d], stage, 64);
            im[d] += __shfl_xor(im[d], stage, 64);
        }
    }

    if (lane == 0) {
        const size_t obase = ((size_t)b * N_NODES + i) * 4;
        const float4 th4 = *(const float4*)(thb + (size_t)i * 4);
        const float4 g4  = *(const float4*)(gamma + obase);
        const float thd[4] = {th4.x, th4.y, th4.z, th4.w};
        const float gd[4]  = {g4.x, g4.y, g4.z, g4.w};
        float t[4];
        float s2 = 0.0f;
        #pragma unroll
        for (int d = 0; d < 4; ++d) {
            float s_i, c_i;
            __sincosf(thd[d], &s_i, &c_i);
            const float coup = (c_i * im[d] - s_i * re[d]) * (1.0f / (float)N_NODES);
            t[d] = gd[d] + coup;   // theta + (gamma-theta) + coupling  (DT=ATTR=1)
            s2 = fmaf(t[d], t[d], s2);
        }
        const float inv = 1.0f / fmaxf(sqrtf(s2), 1e-6f);
        *(float4*)(out + obase) = make_float4(t[0]*inv, t[1]*inv, t[2]*inv, t[3]*inv);
    }
}

extern "C" void kernel_launch(void* const* d_in, const int* in_sizes, int n_in,
                              void* d_out, int out_size, void* d_ws, size_t ws_size,
                              hipStream_t stream) {
    const float* theta = (const float*)d_in[0];
    const float* gamma = (const float*)d_in[1];
    const float* W     = (const float*)d_in[2];
    const float* alpha = (const float*)d_in[3];
    float* out = (float*)d_out;

    const int grid = (N_BATCH * N_NODES) / ROWS_PER_BLOCK;  // 1024 blocks = 4/CU
    hipLaunchKernelGGL(kuramoto_kernel, dim3(grid), dim3(THREADS), 0, stream,
                       theta, gamma, W, alpha, out);
}

// Round 6
// 152.844 us; speedup vs baseline: 1.1806x; 1.0047x over previous
//
#include <hip/hip_runtime.h>
#include <stdint.h>

#define N_NODES 2048
#define N_BATCH 4
#define ROWS_PER_BLOCK 8
#define THREADS 512   // 8 waves, one row per wave

__device__ __forceinline__ uint32_t bf16rn(float x) {
    uint32_t u = __float_as_uint(x);
    u += 0x7fffu + ((u >> 16) & 1u);
    return u >> 16;
}

// Phase-2 W/alpha loads are float4 (global_load_dwordx4, 1 KB/wave-instr):
// R2/R3/R5 all plateaued at 2.85 TB/s demand BW with scalar dword loads
// regardless of occupancy/pipelining; m13's 6.29 TB/s ubench uses dwordx4.
// LDS table is SoA-by-d so per-d reads stay conflict-free ds_read_b128.
__global__ __launch_bounds__(THREADS, 4) void kuramoto_kernel(
    const float* __restrict__ theta,
    const float* __restrict__ gamma,
    const float* __restrict__ W,
    const float* __restrict__ alpha,
    float* __restrict__ out)
{
    // plane d, node j: (bf16(cos th_jd)<<16) | bf16(sin th_jd).  32 KB total.
    __shared__ uint32_t scTab[4][N_NODES];

    const int tid  = threadIdx.x;
    const int lane = tid & 63;
    const int wave = tid >> 6;
    const int b    = blockIdx.x >> 8;                       // 256 blocks per batch
    const int i    = ((blockIdx.x & 255) * ROWS_PER_BLOCK) + wave;  // row in batch

    // ---- Phase 1: stage sin/cos(theta[b,:,:]) into LDS, SoA by d ----
    const float* thb = theta + (size_t)b * (N_NODES * 4);
    #pragma unroll
    for (int g = 0; g < N_NODES / THREADS; ++g) {
        const int j = tid + g * THREADS;
        const float4 u = *(const float4*)(thb + (size_t)j * 4);  // 16B coalesced
        const float th[4] = {u.x, u.y, u.z, u.w};
        #pragma unroll
        for (int d = 0; d < 4; ++d) {
            float s, c;
            __sincosf(th[d], &s, &c);
            scTab[d][j] = (bf16rn(c) << 16) | bf16rn(s);  // stride-1 dword: no conflict
        }
    }
    __syncthreads();

    // ---- Phase 2: complex accumulation over j, float4 loads ----
    // coupling_d = c_i*im_d - s_i*re_d
    //   im_d = sum_j (A*s_jd - B*c_jd),  re_d = sum_j (A*c_jd + B*s_jd)
    //   A = W*cos(alpha), B = W*sin(alpha)
    const size_t rowbase = ((size_t)b * N_NODES + i) * N_NODES;
    const float* Wr = W + rowbase;   // 8 KB aligned
    const float* Ar = alpha + rowbase;

    float re[4] = {0.f, 0.f, 0.f, 0.f};
    float im[4] = {0.f, 0.f, 0.f, 0.f};

    // lane owns j = it*256 + 4*lane .. +3 ; depth-1 register rotate on loads
    float4 w4 = *(const float4*)(Wr + 4 * lane);
    float4 a4 = *(const float4*)(Ar + 4 * lane);

    #pragma unroll
    for (int it = 0; it < N_NODES / 256; ++it) {
        float4 w4n, a4n;
        if (it < N_NODES / 256 - 1) {
            const int nb = (it + 1) * 256 + 4 * lane;
            w4n = *(const float4*)(Wr + nb);
            a4n = *(const float4*)(Ar + nb);
        }
        const int jb = it * 256 + 4 * lane;
        const float wk[4] = {w4.x, w4.y, w4.z, w4.w};
        const float ak[4] = {a4.x, a4.y, a4.z, a4.w};
        float A[4], Bq[4];
        #pragma unroll
        for (int k = 0; k < 4; ++k) {
            float sa, ca;
            __sincosf(ak[k], &sa, &ca);
            A[k]  = wk[k] * ca;
            Bq[k] = wk[k] * sa;
        }
        #pragma unroll
        for (int d = 0; d < 4; ++d) {
            const uint4 t = *(const uint4*)(&scTab[d][jb]);  // b128, 16B/lane: clean
            const uint32_t tw[4] = {t.x, t.y, t.z, t.w};
            #pragma unroll
            for (int k = 0; k < 4; ++k) {
                const float s = __uint_as_float(tw[k] << 16);
                const float c = __uint_as_float(tw[k] & 0xffff0000u);
                re[d] = fmaf(A[k],  c, re[d]);
                re[d] = fmaf(Bq[k], s, re[d]);
                im[d] = fmaf(A[k],  s, im[d]);
                im[d] = fmaf(-Bq[k], c, im[d]);
            }
        }
        w4 = w4n;
        a4 = a4n;
    }

    // ---- Reduction: 6-stage butterfly over 64 lanes, 8 accumulators ----
    #pragma unroll
    for (int stage = 1; stage < 64; stage <<= 1) {
        #pragma unroll
        for (int d = 0; d < 4; ++d) {
            re[d] += __shfl_xor(re[d], stage, 64);
            im[d] += __shfl_xor(im[d], stage, 64);
        }
    }

    if (lane == 0) {
        const size_t obase = ((size_t)b * N_NODES + i) * 4;
        const float4 th4 = *(const float4*)(thb + (size_t)i * 4);
        const float4 g4  = *(const float4*)(gamma + obase);
        const float thd[4] = {th4.x, th4.y, th4.z, th4.w};
        const float gd[4]  = {g4.x, g4.y, g4.z, g4.w};
        float t[4];
        float s2 = 0.0f;
        #pragma unroll
        for (int d = 0; d < 4; ++d) {
            float s_i, c_i;
            __sincosf(thd[d], &s_i, &c_i);
            const float coup = (c_i * im[d] - s_i * re[d]) * (1.0f / (float)N_NODES);
            t[d] = gd[d] + coup;   // theta + (gamma-theta) + coupling  (DT=ATTR=1)
            s2 = fmaf(t[d], t[d], s2);
        }
        const float inv = 1.0f / fmaxf(sqrtf(s2), 1e-6f);
        *(float4*)(out + obase) = make_float4(t[0]*inv, t[1]*inv, t[2]*inv, t[3]*inv);
    }
}

extern "C" void kernel_launch(void* const* d_in, const int* in_sizes, int n_in,
                              void* d_out, int out_size, void* d_ws, size_t ws_size,
                              hipStream_t stream) {
    const float* theta = (const float*)d_in[0];
    const float* gamma = (const float*)d_in[1];
    const float* W     = (const float*)d_in[2];
    const float* alpha = (const float*)d_in[3];
    float* out = (float*)d_out;

    const int grid = (N_BATCH * N_NODES) / ROWS_PER_BLOCK;  // 1024 blocks
    hipLaunchKernelGGL(kuramoto_kernel, dim3(grid), dim3(THREADS), 0, stream,
                       theta, gamma, W, alpha, out);
}